// Round 10
// baseline (280.450 us; speedup 1.0000x reference)
//
#include <hip/hip_runtime.h>

// Decoder block: B=2 T=2048 D=1024 H=16 hd=64 HIDDEN=4096. All f32 in/out,
// bf16 MFMA internally (threshold is bf16-floor).

typedef __bf16 bf16_t;
typedef bf16_t bf16x8 __attribute__((ext_vector_type(8)));
typedef float f32x4 __attribute__((ext_vector_type(4)));

#define M_ROWS 4096   // B*T
#define DMODEL 1024
#define TSEQ   2048
#define NHEAD  16
#define HDIM   64

__device__ __forceinline__ ushort f2bf(float f) {
  union { float f; unsigned u; } v; v.f = f;
  unsigned r = (v.u + 0x7fffu + ((v.u >> 16) & 1u)) >> 16;
  return (ushort)r;
}
__device__ __forceinline__ float bf2f(ushort u) {
  union { unsigned u; float f; } v; v.u = ((unsigned)u) << 16;
  return v.f;
}
__device__ __forceinline__ unsigned cvt_pk_bf16(float a, float b) {
  unsigned r;
  asm("v_cvt_pk_bf16_f32 %0, %1, %2" : "=v"(r) : "v"(a), "v"(b));
  return r;
}
__device__ __forceinline__ void gload_lds16(const void* g, void* l) {
  __builtin_amdgcn_global_load_lds(
      (const __attribute__((address_space(1))) unsigned*)g,
      (__attribute__((address_space(3))) unsigned*)l, 16, 0, 0);
}
__device__ __forceinline__ f32x4 mfma16(bf16x8 a, bf16x8 b, f32x4 c) {
  return __builtin_amdgcn_mfma_f32_16x16x32_bf16(a, b, c, 0, 0, 0);
}
__device__ __forceinline__ float gelu_f(float x) {
  float y = 0.7978845608028654f * (x + 0.044715f * x * x * x);
  float e = __expf(2.0f * y);
  float t = 1.0f - 2.0f / (e + 1.0f);   // tanh(y), overflow-safe
  return 0.5f * x * (1.0f + t);
}

// ---------------- weight transpose + f32->bf16 -----------------------------
__global__ __launch_bounds__(256)
void transpose_bf16(const float* __restrict__ src, ushort* __restrict__ dst,
                    int K, int N) {
  __shared__ float t[32][33];
  int n0 = blockIdx.x * 32, k0 = blockIdx.y * 32;
  int tx = threadIdx.x & 31, ty = threadIdx.x >> 5;
#pragma unroll
  for (int i = 0; i < 4; i++) {
    int k = ty + i * 8;
    t[k][tx] = src[(size_t)(k0 + k) * N + n0 + tx];
  }
  __syncthreads();
#pragma unroll
  for (int i = 0; i < 4; i++) {
    int nn = ty + i * 8;
    dst[(size_t)(n0 + nn) * K + k0 + tx] = f2bf(t[tx][nn]);
  }
}

// ---------------- layernorm (f32 in, bf16 out) -----------------------------
__global__ __launch_bounds__(256)
void ln_kernel(const float* __restrict__ x, const float* __restrict__ sc,
               const float* __restrict__ bi, ushort* __restrict__ out) {
  int row = blockIdx.x;
  int tid = threadIdx.x;
  const float4 v = *(const float4*)&x[(size_t)row * DMODEL + tid * 4];
  float s = v.x + v.y + v.z + v.w;
  float s2 = v.x * v.x + v.y * v.y + v.z * v.z + v.w * v.w;
#pragma unroll
  for (int off = 32; off > 0; off >>= 1) {
    s += __shfl_down(s, off);
    s2 += __shfl_down(s2, off);
  }
  __shared__ float red[8];
  int lane = tid & 63, w = tid >> 6;
  if (lane == 0) { red[w * 2] = s; red[w * 2 + 1] = s2; }
  __syncthreads();
  float S = red[0] + red[2] + red[4] + red[6];
  float S2 = red[1] + red[3] + red[5] + red[7];
  float mu = S * (1.0f / DMODEL);
  float var = S2 * (1.0f / DMODEL) - mu * mu;
  float rs = rsqrtf(var + 1e-6f);
  float4 scv = *(const float4*)&sc[tid * 4];
  float4 biv = *(const float4*)&bi[tid * 4];
  ushort4 o;
  o.x = f2bf((v.x - mu) * rs * scv.x + biv.x);
  o.y = f2bf((v.y - mu) * rs * scv.y + biv.y);
  o.z = f2bf((v.z - mu) * rs * scv.z + biv.z);
  o.w = f2bf((v.w - mu) * rs * scv.w + biv.w);
  *(ushort4*)&out[(size_t)row * DMODEL + tid * 4] = o;
}

// ---------------- rope table -----------------------------------------------
__global__ __launch_bounds__(256)
void rope_table(const int* __restrict__ positions, float2* __restrict__ tab) {
  int i = blockIdx.x * 256 + threadIdx.x;  // T*32
  int t = i >> 5, f = i & 31;
  float inv = __expf(-(float)f * (1.0f / 32.0f) * 9.210340371976184f);
  float a = (float)positions[t] * inv;
  tab[i] = make_float2(cosf(a), sinf(a));
}

// ---------------- rope apply + QKV reshape ---------------------------------
__global__ __launch_bounds__(256)
void rope_apply(const ushort* __restrict__ qkv, const float2* __restrict__ tab,
                ushort* __restrict__ Q, ushort* __restrict__ Kd,
                ushort* __restrict__ VT) {
  __shared__ ushort vt[64][66];
  int t0 = blockIdx.x * 64;
  int bh = blockIdx.y;
  int b = bh >> 4, h = bh & 15;
  int f = threadIdx.x & 31, tg = threadIdx.x >> 5;  // tg 0..7
#pragma unroll
  for (int i = 0; i < 8; i++) {
    int tt = tg * 8 + i;
    int t = t0 + tt;
    const ushort* qr = qkv + (size_t)(b * TSEQ + t) * 3072 + h * 64 + f;
    float2 cs = tab[t * 32 + f];
    float c = cs.x, s = cs.y;
    float q1 = bf2f(qr[0]),    q2 = bf2f(qr[32]);
    float k1 = bf2f(qr[1024]), k2 = bf2f(qr[1056]);
    ushort* Qp = Q + ((size_t)bh * TSEQ + t) * HDIM;
    ushort* Kp = Kd + ((size_t)bh * TSEQ + t) * HDIM;
    Qp[f]      = f2bf(q1 * c - q2 * s);
    Qp[f + 32] = f2bf(q1 * s + q2 * c);
    Kp[f]      = f2bf(k1 * c - k2 * s);
    Kp[f + 32] = f2bf(k1 * s + k2 * c);
    vt[f][tt]      = qr[2048];   // V needs no rope: raw bf16 copy
    vt[f + 32][tt] = qr[2080];
  }
  __syncthreads();
  int t = threadIdx.x & 63, fg = threadIdx.x >> 6;  // fg 0..3
  ushort* Vp = VT + (size_t)bh * HDIM * TSEQ + t0 + t;
#pragma unroll
  for (int j = 0; j < 16; j++) {
    int ff = fg * 16 + j;
    Vp[(size_t)ff * TSEQ] = vt[ff][t];
  }
}

// ---------------- attention (flash, causal, 4-wave LDS-staged) -------------
// (unchanged — GEMM is the current bottleneck)
__global__ __launch_bounds__(256, 4)
void attn_kernel(const ushort* __restrict__ Q, const ushort* __restrict__ Kd,
                 const ushort* __restrict__ VT, ushort* __restrict__ O) {
  int bh = blockIdx.x;
  int qb = 31 - (int)blockIdx.y;    // longest-first
  int nt = qb + 1;                  // 64-key tiles
  int tid = threadIdx.x;
  int lane = tid & 63, w = tid >> 6;
  int qw = qb * 64 + w * 16;
  int lr = lane & 15, lg = lane >> 4;
  int q_abs = qw + lr;

  const ushort* Qb = Q + (size_t)bh * TSEQ * HDIM;
  const ushort* Kb = Kd + (size_t)bh * TSEQ * HDIM;
  const ushort* Vb = VT + (size_t)bh * HDIM * TSEQ;

  __shared__ ushort lK[2][64 * 64];
  __shared__ ushort lV[2][64 * 64];
  __shared__ ushort pt[4][16 * 64];
  ushort* myp = pt[w];

  int srow0 = tid >> 3, sch = tid & 7;

  auto stage = [&](int buf, int kt) {
#pragma unroll
    for (int c = 0; c < 2; c++) {
      int r = c * 32 + srow0;
      int gch = sch ^ (r & 7);
      gload_lds16(Kb + (size_t)(kt + r) * HDIM + gch * 8,
                  &lK[buf][c * 2048 + tid * 8]);
      gload_lds16(Vb + (size_t)r * TSEQ + kt + gch * 8,
                  &lV[buf][c * 2048 + tid * 8]);
    }
  };

  const float QS = 0.125f * 1.44269504088896340736f;
  bf16x8 aq0 = *(const bf16x8*)&Qb[(size_t)q_abs * HDIM + lg * 8];
  bf16x8 aq1 = *(const bf16x8*)&Qb[(size_t)q_abs * HDIM + 32 + lg * 8];
#pragma unroll
  for (int j = 0; j < 8; j++) {
    aq0[j] = (bf16_t)((float)aq0[j] * QS);
    aq1[j] = (bf16_t)((float)aq1[j] * QS);
  }

  float m_run = -1e30f, l_run = 0.0f;   // per-lane: stats of q-row lr
  f32x4 o[4] = {};                      // o[d][r] = O[q=lr][d*16+lg*4+r]

  stage(0, 0);
  __syncthreads();

  for (int it = 0; it < nt; ++it) {
    int kt = it * 64;
    int buf = it & 1;
    bool diag = (it == nt - 1);

    if (it + 1 < nt) stage(buf ^ 1, kt + 64);

    // QK^T (swapped): sa[cb][r] = S[k=kt+cb*16+lg*4+r][q=lr]
    f32x4 sa[4];
#pragma unroll
    for (int cb = 0; cb < 4; cb++) {
      int row = cb * 16 + lr;
      const ushort* kp = &lK[buf][row * 64];
      bf16x8 k0 = *(const bf16x8*)(kp + (((lg    ) ^ (row & 7)) << 3));
      bf16x8 k1 = *(const bf16x8*)(kp + (((lg + 4) ^ (row & 7)) << 3));
      f32x4 z = {};
      z = mfma16(k0, aq0, z);
      sa[cb] = mfma16(k1, aq1, z);
    }

    if (diag) {
#pragma unroll
      for (int cb = 0; cb < 4; cb++)
#pragma unroll
        for (int r = 0; r < 4; r++)
          if (kt + cb * 16 + lg * 4 + r > q_abs) sa[cb][r] = -1e30f;
    }

    // row max (tree + 2 shfl)
    f32x4 m4;
#pragma unroll
    for (int r = 0; r < 4; r++)
      m4[r] = fmaxf(fmaxf(sa[0][r], sa[1][r]), fmaxf(sa[2][r], sa[3][r]));
    float mx = fmaxf(fmaxf(m4[0], m4[1]), fmaxf(m4[2], m4[3]));
    mx = fmaxf(mx, __shfl_xor(mx, 16, 64));
    mx = fmaxf(mx, __shfl_xor(mx, 32, 64));
    float mn = fmaxf(m_run, mx);
    float rescale = __builtin_amdgcn_exp2f(m_run - mn);
    m_run = mn;

    // exp2 + sum + pack
    float ps = 0.0f;
    uint2 pk[4];
#pragma unroll
    for (int cb = 0; cb < 4; cb++) {
      float p0 = __builtin_amdgcn_exp2f(sa[cb][0] - mn);
      float p1 = __builtin_amdgcn_exp2f(sa[cb][1] - mn);
      float p2 = __builtin_amdgcn_exp2f(sa[cb][2] - mn);
      float p3 = __builtin_amdgcn_exp2f(sa[cb][3] - mn);
      ps += (p0 + p1) + (p2 + p3);
      pk[cb].x = cvt_pk_bf16(p0, p1);
      pk[cb].y = cvt_pk_bf16(p2, p3);
    }
    ps += __shfl_xor(ps, 16, 64);
    ps += __shfl_xor(ps, 32, 64);
    l_run = l_run * rescale + ps;

    // store P (swizzled, wave-local)
#pragma unroll
    for (int cb = 0; cb < 4; cb++)
      *(uint2*)&myp[lr * 64 + (((cb * 4 + lg) ^ lr) << 2)] = pk[cb];

    // rescale o (scalar per lane — q is lane-local)
#pragma unroll
    for (int d = 0; d < 4; d++)
#pragma unroll
      for (int r = 0; r < 4; r++) o[d][r] *= rescale;

    // read P B-fragments: lane needs P[q=lr][k = c*32 + lg*8 .. +8]
    union U8 { uint2 h[2]; bf16x8 v; };
    U8 t0, t1;
    t0.h[0] = *(const uint2*)&myp[lr * 64 + (((lg * 2    ) ^ lr) << 2)];
    t0.h[1] = *(const uint2*)&myp[lr * 64 + (((lg * 2 + 1) ^ lr) << 2)];
    t1.h[0] = *(const uint2*)&myp[lr * 64 + (((8 + lg * 2    ) ^ lr) << 2)];
    t1.h[1] = *(const uint2*)&myp[lr * 64 + (((8 + lg * 2 + 1) ^ lr) << 2)];

    // PV (swapped): o[d] += V^T_frag x P_frag  -> O^T, q = lr
#pragma unroll
    for (int d = 0; d < 4; d++) {
      int row = d * 16 + lr;
      const ushort* vp = &lV[buf][row * 64];
      bf16x8 va0 = *(const bf16x8*)(vp + (((lg    ) ^ (row & 7)) << 3));
      bf16x8 va1 = *(const bf16x8*)(vp + (((lg + 4) ^ (row & 7)) << 3));
      o[d] = mfma16(va0, t0.v, o[d]);
      o[d] = mfma16(va1, t1.v, o[d]);
    }

    __syncthreads();
  }

  int b = bh >> 4, h = bh & 15;
  float linv = 1.0f / l_run;
  size_t obase = (size_t)(b * TSEQ + qw + lr) * DMODEL + h * 64;
#pragma unroll
  for (int d = 0; d < 4; d++) {
    uint2 st;
    st.x = cvt_pk_bf16(o[d][0] * linv, o[d][1] * linv);
    st.y = cvt_pk_bf16(o[d][2] * linv, o[d][3] * linv);
    *(uint2*)&O[obase + d * 16 + lg * 4] = st;
  }
}

// ---------------- GEMM: ring-4 counted-vmcnt pipeline (T3+T4) --------------
// C(M,N) = A(M,K) @ Bt(N,K)^T. BM=128, BN template (128/64), BK=32,
// 4 waves 2x2(BN=128) / 2x2(BN=64 with NF=2). Ring of 4 LDS buffers;
// prologue stages tiles 0,1; body of tile t issues stage(t+2); top of tile t
// waits COUNTED vmcnt(loads-per-stage) -- tile t's loads were issued 2 full
// tiles ago, so the wait is ~free (T4: never drain to 0 in the main loop).
// Correctness: each wave's own stage(t+1) loads retire before its barrier
// arrival => after barrier buffer complete for all waves. stage(t+2) writes
// buf[(t+2)&3] != buf[t&3]; barrier skew < 1 segment => no WAR hazard.
// Swizzle for BK=32: chunk ^= (row>>1)&3 (both-sides: linear LDS dest +
// inverse-swizzled global source + swizzled read) -> uniform bank spread.
template <int EPI, int BN>
__global__ __launch_bounds__(256)
void gemm_kernel(const ushort* __restrict__ A, const ushort* __restrict__ Bt,
                 void* __restrict__ Cout, const float* __restrict__ bias,
                 const float* __restrict__ resid, int M, int N, int K,
                 int nbn) {
  constexpr int NF = BN / 32;           // n-frags per wave (4 or 2)
  constexpr int VC = 2 + BN / 64;       // loads per stage: A(2) + B(BN/64)
  __shared__ ushort lA[4][128 * 32];
  __shared__ ushort lB[4][BN * 32];
  int tid = threadIdx.x;
  int lane = tid & 63, w = tid >> 6;
  int wm = w >> 1, wn = w & 1;

  int nwg = gridDim.x;
  int cpx = nwg >> 3;
  int wg = ((int)blockIdx.x & 7) * cpx + ((int)blockIdx.x >> 3);
  int bm = wg / nbn, bn = wg % nbn;

  f32x4 acc[4][NF] = {};

  const ushort* Ab = A + (size_t)bm * 128 * K;
  const ushort* Bb = Bt + (size_t)bn * BN * K;
  int lrow = lane & 15, lg = lane >> 4;
  int srow = tid >> 2, sch = tid & 3;   // staging: 64 rows/instr, 4 chunks

  auto stage = [&](int buf, int k0) {
#pragma unroll
    for (int c = 0; c < 2; c++) {
      int r = c * 64 + srow;
      int gch = sch ^ ((r >> 1) & 3);
      gload_lds16(Ab + (size_t)r * K + k0 + gch * 8,
                  &lA[buf][c * 2048 + tid * 8]);
    }
#pragma unroll
    for (int c = 0; c < BN / 64; c++) {
      int r = c * 64 + srow;
      int gch = sch ^ ((r >> 1) & 3);
      gload_lds16(Bb + (size_t)r * K + k0 + gch * 8,
                  &lB[buf][c * 2048 + tid * 8]);
    }
  };

  int nt = K >> 5;
  stage(0, 0);
  stage(1, 32);

  for (int t = 0; t < nt; ++t) {
    int cur = t & 3;

    // ---- counted wait: tile t's loads are 2 tiles old; only stage(t+1)
    // ---- (VC loads) may remain outstanding. Never drains in steady state.
    if (t < nt - 1) {
      if constexpr (BN == 128)
        asm volatile("s_waitcnt vmcnt(4)" ::: "memory");
      else
        asm volatile("s_waitcnt vmcnt(3)" ::: "memory");
    } else {
      asm volatile("s_waitcnt vmcnt(0)" ::: "memory");
    }
    __builtin_amdgcn_s_barrier();

    // ---- issue stage(t+2) into buf[(t+2)&3] (never the buffer being read)
    if (t + 2 < nt) stage((t + 2) & 3, (t + 2) << 5);

    // ---- ds_read current tile fragments ----
    bf16x8 af[4], bfr[NF];
#pragma unroll
    for (int m = 0; m < 4; m++) {
      int row = wm * 64 + m * 16 + lrow;
      af[m] = *(const bf16x8*)&lA[cur][row * 32 + ((lg ^ ((row >> 1) & 3)) << 3)];
    }
#pragma unroll
    for (int n = 0; n < NF; n++) {
      int row = wn * (BN / 2) + n * 16 + lrow;
      bfr[n] = *(const bf16x8*)&lB[cur][row * 32 + ((lg ^ ((row >> 1) & 3)) << 3)];
    }

    // ---- MFMA ----
    __builtin_amdgcn_s_setprio(1);
#pragma unroll
    for (int m = 0; m < 4; m++)
#pragma unroll
      for (int n = 0; n < NF; n++)
        acc[m][n] = mfma16(af[m], bfr[n], acc[m][n]);
    __builtin_amdgcn_s_setprio(0);
  }

#pragma unroll
  for (int m = 0; m < 4; m++) {
    int rbase = bm * 128 + wm * 64 + m * 16 + (lane >> 4) * 4;
#pragma unroll
    for (int n = 0; n < NF; n++) {
      int c = bn * BN + wn * (BN / 2) + n * 16 + (lane & 15);
#pragma unroll
      for (int r = 0; r < 4; r++) {
        float v = acc[m][n][r];
        size_t idx = (size_t)(rbase + r) * N + c;
        if constexpr (EPI == 0) {
          ((ushort*)Cout)[idx] = f2bf(v);
        } else if constexpr (EPI == 1) {
          ((float*)Cout)[idx] = v + resid[idx];
        } else if constexpr (EPI == 2) {
          ((ushort*)Cout)[idx] = f2bf(gelu_f(v + bias[c]));
        } else {
          ((float*)Cout)[idx] = v + bias[c] + resid[idx];
        }
      }
    }
  }
}

// ---------------------------------------------------------------------------
extern "C" void kernel_launch(void* const* d_in, const int* in_sizes, int n_in,
                              void* d_out, int out_size, void* d_ws,
                              size_t ws_size, hipStream_t stream) {
  const float* x      = (const float*)d_in[0];
  const int* positions = (const int*)d_in[1];
  const float* ln1_s  = (const float*)d_in[3];
  const float* ln1_b  = (const float*)d_in[4];
  const float* w_qkv  = (const float*)d_in[5];
  const float* w_o    = (const float*)d_in[6];
  const float* ln2_s  = (const float*)d_in[7];
  const float* ln2_b  = (const float*)d_in[8];
  const float* w1     = (const float*)d_in[9];
  const float* b1     = (const float*)d_in[10];
  const float* w2     = (const float*)d_in[11];
  const float* b2     = (const float*)d_in[12];
  float* out = (float*)d_out;

  char* ws = (char*)d_ws;
  size_t off = 0;
  auto nxt = [&](size_t bytes) {
    char* p = ws + off;
    off += (bytes + 255) & ~(size_t)255;
    return p;
  };
  ushort* wqkvT = (ushort*)nxt(3072ULL * 1024 * 2);
  ushort* woT   = (ushort*)nxt(1024ULL * 1024 * 2);
  ushort* w1T   = (ushort*)nxt(4096ULL * 1024 * 2);
  ushort* w2T   = (ushort*)nxt(1024ULL * 4096 * 2);
  ushort* h1    = (ushort*)nxt((size_t)M_ROWS * DMODEL * 2);
  ushort* qkv   = (ushort*)nxt((size_t)M_ROWS * 3072 * 2);
  ushort* Qb    = (ushort*)nxt(2ULL * NHEAD * TSEQ * HDIM * 2);
  ushort* Kb    = (ushort*)nxt(2ULL * NHEAD * TSEQ * HDIM * 2);
  ushort* VTb   = (ushort*)nxt(2ULL * NHEAD * TSEQ * HDIM * 2);
  ushort* attn  = (ushort*)nxt((size_t)M_ROWS * DMODEL * 2);
  float*  x2    = (float*)nxt((size_t)M_ROWS * DMODEL * 4);
  ushort* h2    = (ushort*)nxt((size_t)M_ROWS * DMODEL * 2);
  ushort* mid   = (ushort*)nxt((size_t)M_ROWS * 4096 * 2);
  float2* tab   = (float2*)nxt((size_t)TSEQ * 32 * 8);

  transpose_bf16<<<dim3(3072 / 32, 1024 / 32), 256, 0, stream>>>(w_qkv, wqkvT, 1024, 3072);
  transpose_bf16<<<dim3(1024 / 32, 1024 / 32), 256, 0, stream>>>(w_o, woT, 1024, 1024);
  transpose_bf16<<<dim3(4096 / 32, 1024 / 32), 256, 0, stream>>>(w1, w1T, 1024, 4096);
  transpose_bf16<<<dim3(1024 / 32, 4096 / 32), 256, 0, stream>>>(w2, w2T, 4096, 1024);
  rope_table<<<(TSEQ * 32) / 256, 256, 0, stream>>>(positions, tab);
  ln_kernel<<<M_ROWS, 256, 0, stream>>>(x, ln1_s, ln1_b, h1);
  // qkv: M=4096 N=3072 K=1024, 128x128 tiles -> 768 wgs
  gemm_kernel<0, 128><<<768, 256, 0, stream>>>(h1, wqkvT, qkv, nullptr, nullptr, 4096, 3072, 1024, 24);
  rope_apply<<<dim3(TSEQ / 64, 2 * NHEAD), 256, 0, stream>>>(qkv, tab, Qb, Kb, VTb);
  attn_kernel<<<dim3(32, 32), 256, 0, stream>>>(Qb, Kb, VTb, attn);
  // wo: M=4096 N=1024 K=1024, 128x64 tiles -> 512 wgs
  gemm_kernel<1, 64><<<512, 256, 0, stream>>>(attn, woT, x2, nullptr, x, 4096, 1024, 1024, 16);
  ln_kernel<<<M_ROWS, 256, 0, stream>>>(x2, ln2_s, ln2_b, h2);
  // ffn1: M=4096 N=4096 K=1024, 128x128 tiles -> 1024 wgs
  gemm_kernel<2, 128><<<1024, 256, 0, stream>>>(h2, w1T, mid, b1, nullptr, 4096, 4096, 1024, 32);
  // ffn2: M=4096 N=1024 K=4096, 128x64 tiles -> 512 wgs
  gemm_kernel<3, 64><<<512, 256, 0, stream>>>(mid, w2T, out, b2, x2, 4096, 1024, 4096, 16);
}

// Round 11
// 222.142 us; speedup vs baseline: 1.2625x; 1.2625x over previous
//
#include <hip/hip_runtime.h>

// Decoder block: B=2 T=2048 D=1024 H=16 hd=64 HIDDEN=4096. All f32 in/out,
// bf16 MFMA internally (threshold is bf16-floor).

typedef __bf16 bf16_t;
typedef bf16_t bf16x8 __attribute__((ext_vector_type(8)));
typedef float f32x4 __attribute__((ext_vector_type(4)));

#define M_ROWS 4096   // B*T
#define DMODEL 1024
#define TSEQ   2048
#define NHEAD  16
#define HDIM   64

__device__ __forceinline__ ushort f2bf(float f) {
  union { float f; unsigned u; } v; v.f = f;
  unsigned r = (v.u + 0x7fffu + ((v.u >> 16) & 1u)) >> 16;
  return (ushort)r;
}
__device__ __forceinline__ float bf2f(ushort u) {
  union { unsigned u; float f; } v; v.u = ((unsigned)u) << 16;
  return v.f;
}
__device__ __forceinline__ unsigned cvt_pk_bf16(float a, float b) {
  unsigned r;
  asm("v_cvt_pk_bf16_f32 %0, %1, %2" : "=v"(r) : "v"(a), "v"(b));
  return r;
}
__device__ __forceinline__ void gload_lds16(const void* g, void* l) {
  __builtin_amdgcn_global_load_lds(
      (const __attribute__((address_space(1))) unsigned*)g,
      (__attribute__((address_space(3))) unsigned*)l, 16, 0, 0);
}
__device__ __forceinline__ f32x4 mfma16(bf16x8 a, bf16x8 b, f32x4 c) {
  return __builtin_amdgcn_mfma_f32_16x16x32_bf16(a, b, c, 0, 0, 0);
}
__device__ __forceinline__ float gelu_f(float x) {
  float y = 0.7978845608028654f * (x + 0.044715f * x * x * x);
  float e = __expf(2.0f * y);
  float t = 1.0f - 2.0f / (e + 1.0f);   // tanh(y), overflow-safe
  return 0.5f * x * (1.0f + t);
}

// ---------------- weight transpose + f32->bf16 -----------------------------
__global__ __launch_bounds__(256)
void transpose_bf16(const float* __restrict__ src, ushort* __restrict__ dst,
                    int K, int N) {
  __shared__ float t[32][33];
  int n0 = blockIdx.x * 32, k0 = blockIdx.y * 32;
  int tx = threadIdx.x & 31, ty = threadIdx.x >> 5;
#pragma unroll
  for (int i = 0; i < 4; i++) {
    int k = ty + i * 8;
    t[k][tx] = src[(size_t)(k0 + k) * N + n0 + tx];
  }
  __syncthreads();
#pragma unroll
  for (int i = 0; i < 4; i++) {
    int nn = ty + i * 8;
    dst[(size_t)(n0 + nn) * K + k0 + tx] = f2bf(t[tx][nn]);
  }
}

// ---------------- layernorm (f32 in, bf16 out) -----------------------------
__global__ __launch_bounds__(256)
void ln_kernel(const float* __restrict__ x, const float* __restrict__ sc,
               const float* __restrict__ bi, ushort* __restrict__ out) {
  int row = blockIdx.x;
  int tid = threadIdx.x;
  const float4 v = *(const float4*)&x[(size_t)row * DMODEL + tid * 4];
  float s = v.x + v.y + v.z + v.w;
  float s2 = v.x * v.x + v.y * v.y + v.z * v.z + v.w * v.w;
#pragma unroll
  for (int off = 32; off > 0; off >>= 1) {
    s += __shfl_down(s, off);
    s2 += __shfl_down(s2, off);
  }
  __shared__ float red[8];
  int lane = tid & 63, w = tid >> 6;
  if (lane == 0) { red[w * 2] = s; red[w * 2 + 1] = s2; }
  __syncthreads();
  float S = red[0] + red[2] + red[4] + red[6];
  float S2 = red[1] + red[3] + red[5] + red[7];
  float mu = S * (1.0f / DMODEL);
  float var = S2 * (1.0f / DMODEL) - mu * mu;
  float rs = rsqrtf(var + 1e-6f);
  float4 scv = *(const float4*)&sc[tid * 4];
  float4 biv = *(const float4*)&bi[tid * 4];
  ushort4 o;
  o.x = f2bf((v.x - mu) * rs * scv.x + biv.x);
  o.y = f2bf((v.y - mu) * rs * scv.y + biv.y);
  o.z = f2bf((v.z - mu) * rs * scv.z + biv.z);
  o.w = f2bf((v.w - mu) * rs * scv.w + biv.w);
  *(ushort4*)&out[(size_t)row * DMODEL + tid * 4] = o;
}

// ---------------- rope table -----------------------------------------------
__global__ __launch_bounds__(256)
void rope_table(const int* __restrict__ positions, float2* __restrict__ tab) {
  int i = blockIdx.x * 256 + threadIdx.x;  // T*32
  int t = i >> 5, f = i & 31;
  float inv = __expf(-(float)f * (1.0f / 32.0f) * 9.210340371976184f);
  float a = (float)positions[t] * inv;
  tab[i] = make_float2(cosf(a), sinf(a));
}

// ---------------- rope apply + QKV reshape ---------------------------------
__global__ __launch_bounds__(256)
void rope_apply(const ushort* __restrict__ qkv, const float2* __restrict__ tab,
                ushort* __restrict__ Q, ushort* __restrict__ Kd,
                ushort* __restrict__ VT) {
  __shared__ ushort vt[64][66];
  int t0 = blockIdx.x * 64;
  int bh = blockIdx.y;
  int b = bh >> 4, h = bh & 15;
  int f = threadIdx.x & 31, tg = threadIdx.x >> 5;  // tg 0..7
#pragma unroll
  for (int i = 0; i < 8; i++) {
    int tt = tg * 8 + i;
    int t = t0 + tt;
    const ushort* qr = qkv + (size_t)(b * TSEQ + t) * 3072 + h * 64 + f;
    float2 cs = tab[t * 32 + f];
    float c = cs.x, s = cs.y;
    float q1 = bf2f(qr[0]),    q2 = bf2f(qr[32]);
    float k1 = bf2f(qr[1024]), k2 = bf2f(qr[1056]);
    ushort* Qp = Q + ((size_t)bh * TSEQ + t) * HDIM;
    ushort* Kp = Kd + ((size_t)bh * TSEQ + t) * HDIM;
    Qp[f]      = f2bf(q1 * c - q2 * s);
    Qp[f + 32] = f2bf(q1 * s + q2 * c);
    Kp[f]      = f2bf(k1 * c - k2 * s);
    Kp[f + 32] = f2bf(k1 * s + k2 * c);
    vt[f][tt]      = qr[2048];   // V needs no rope: raw bf16 copy
    vt[f + 32][tt] = qr[2080];
  }
  __syncthreads();
  int t = threadIdx.x & 63, fg = threadIdx.x >> 6;  // fg 0..3
  ushort* Vp = VT + (size_t)bh * HDIM * TSEQ + t0 + t;
#pragma unroll
  for (int j = 0; j < 16; j++) {
    int ff = fg * 16 + j;
    Vp[(size_t)ff * TSEQ] = vt[ff][t];
  }
}

// ---------------- attention (flash, causal, 4-wave LDS-staged) -------------
// (unchanged — GEMM is the current bottleneck)
__global__ __launch_bounds__(256, 4)
void attn_kernel(const ushort* __restrict__ Q, const ushort* __restrict__ Kd,
                 const ushort* __restrict__ VT, ushort* __restrict__ O) {
  int bh = blockIdx.x;
  int qb = 31 - (int)blockIdx.y;    // longest-first
  int nt = qb + 1;                  // 64-key tiles
  int tid = threadIdx.x;
  int lane = tid & 63, w = tid >> 6;
  int qw = qb * 64 + w * 16;
  int lr = lane & 15, lg = lane >> 4;
  int q_abs = qw + lr;

  const ushort* Qb = Q + (size_t)bh * TSEQ * HDIM;
  const ushort* Kb = Kd + (size_t)bh * TSEQ * HDIM;
  const ushort* Vb = VT + (size_t)bh * HDIM * TSEQ;

  __shared__ ushort lK[2][64 * 64];
  __shared__ ushort lV[2][64 * 64];
  __shared__ ushort pt[4][16 * 64];
  ushort* myp = pt[w];

  int srow0 = tid >> 3, sch = tid & 7;

  auto stage = [&](int buf, int kt) {
#pragma unroll
    for (int c = 0; c < 2; c++) {
      int r = c * 32 + srow0;
      int gch = sch ^ (r & 7);
      gload_lds16(Kb + (size_t)(kt + r) * HDIM + gch * 8,
                  &lK[buf][c * 2048 + tid * 8]);
      gload_lds16(Vb + (size_t)r * TSEQ + kt + gch * 8,
                  &lV[buf][c * 2048 + tid * 8]);
    }
  };

  const float QS = 0.125f * 1.44269504088896340736f;
  bf16x8 aq0 = *(const bf16x8*)&Qb[(size_t)q_abs * HDIM + lg * 8];
  bf16x8 aq1 = *(const bf16x8*)&Qb[(size_t)q_abs * HDIM + 32 + lg * 8];
#pragma unroll
  for (int j = 0; j < 8; j++) {
    aq0[j] = (bf16_t)((float)aq0[j] * QS);
    aq1[j] = (bf16_t)((float)aq1[j] * QS);
  }

  float m_run = -1e30f, l_run = 0.0f;   // per-lane: stats of q-row lr
  f32x4 o[4] = {};                      // o[d][r] = O[q=lr][d*16+lg*4+r]

  stage(0, 0);
  __syncthreads();

  for (int it = 0; it < nt; ++it) {
    int kt = it * 64;
    int buf = it & 1;
    bool diag = (it == nt - 1);

    if (it + 1 < nt) stage(buf ^ 1, kt + 64);

    // QK^T (swapped): sa[cb][r] = S[k=kt+cb*16+lg*4+r][q=lr]
    f32x4 sa[4];
#pragma unroll
    for (int cb = 0; cb < 4; cb++) {
      int row = cb * 16 + lr;
      const ushort* kp = &lK[buf][row * 64];
      bf16x8 k0 = *(const bf16x8*)(kp + (((lg    ) ^ (row & 7)) << 3));
      bf16x8 k1 = *(const bf16x8*)(kp + (((lg + 4) ^ (row & 7)) << 3));
      f32x4 z = {};
      z = mfma16(k0, aq0, z);
      sa[cb] = mfma16(k1, aq1, z);
    }

    if (diag) {
#pragma unroll
      for (int cb = 0; cb < 4; cb++)
#pragma unroll
        for (int r = 0; r < 4; r++)
          if (kt + cb * 16 + lg * 4 + r > q_abs) sa[cb][r] = -1e30f;
    }

    // row max (tree + 2 shfl)
    f32x4 m4;
#pragma unroll
    for (int r = 0; r < 4; r++)
      m4[r] = fmaxf(fmaxf(sa[0][r], sa[1][r]), fmaxf(sa[2][r], sa[3][r]));
    float mx = fmaxf(fmaxf(m4[0], m4[1]), fmaxf(m4[2], m4[3]));
    mx = fmaxf(mx, __shfl_xor(mx, 16, 64));
    mx = fmaxf(mx, __shfl_xor(mx, 32, 64));
    float mn = fmaxf(m_run, mx);
    float rescale = __builtin_amdgcn_exp2f(m_run - mn);
    m_run = mn;

    // exp2 + sum + pack
    float ps = 0.0f;
    uint2 pk[4];
#pragma unroll
    for (int cb = 0; cb < 4; cb++) {
      float p0 = __builtin_amdgcn_exp2f(sa[cb][0] - mn);
      float p1 = __builtin_amdgcn_exp2f(sa[cb][1] - mn);
      float p2 = __builtin_amdgcn_exp2f(sa[cb][2] - mn);
      float p3 = __builtin_amdgcn_exp2f(sa[cb][3] - mn);
      ps += (p0 + p1) + (p2 + p3);
      pk[cb].x = cvt_pk_bf16(p0, p1);
      pk[cb].y = cvt_pk_bf16(p2, p3);
    }
    ps += __shfl_xor(ps, 16, 64);
    ps += __shfl_xor(ps, 32, 64);
    l_run = l_run * rescale + ps;

    // store P (swizzled, wave-local)
#pragma unroll
    for (int cb = 0; cb < 4; cb++)
      *(uint2*)&myp[lr * 64 + (((cb * 4 + lg) ^ lr) << 2)] = pk[cb];

    // rescale o (scalar per lane — q is lane-local)
#pragma unroll
    for (int d = 0; d < 4; d++)
#pragma unroll
      for (int r = 0; r < 4; r++) o[d][r] *= rescale;

    // read P B-fragments: lane needs P[q=lr][k = c*32 + lg*8 .. +8]
    union U8 { uint2 h[2]; bf16x8 v; };
    U8 t0, t1;
    t0.h[0] = *(const uint2*)&myp[lr * 64 + (((lg * 2    ) ^ lr) << 2)];
    t0.h[1] = *(const uint2*)&myp[lr * 64 + (((lg * 2 + 1) ^ lr) << 2)];
    t1.h[0] = *(const uint2*)&myp[lr * 64 + (((8 + lg * 2    ) ^ lr) << 2)];
    t1.h[1] = *(const uint2*)&myp[lr * 64 + (((8 + lg * 2 + 1) ^ lr) << 2)];

    // PV (swapped): o[d] += V^T_frag x P_frag  -> O^T, q = lr
#pragma unroll
    for (int d = 0; d < 4; d++) {
      int row = d * 16 + lr;
      const ushort* vp = &lV[buf][row * 64];
      bf16x8 va0 = *(const bf16x8*)(vp + (((lg    ) ^ (row & 7)) << 3));
      bf16x8 va1 = *(const bf16x8*)(vp + (((lg + 4) ^ (row & 7)) << 3));
      o[d] = mfma16(va0, t0.v, o[d]);
      o[d] = mfma16(va1, t1.v, o[d]);
    }

    __syncthreads();
  }

  int b = bh >> 4, h = bh & 15;
  float linv = 1.0f / l_run;
  size_t obase = (size_t)(b * TSEQ + qw + lr) * DMODEL + h * 64;
#pragma unroll
  for (int d = 0; d < 4; d++) {
    uint2 st;
    st.x = cvt_pk_bf16(o[d][0] * linv, o[d][1] * linv);
    st.y = cvt_pk_bf16(o[d][2] * linv, o[d][3] * linv);
    *(uint2*)&O[obase + d * 16 + lg * 4] = st;
  }
}

// ---------------- GEMM 256x256 counted-vmcnt pipeline (T3+T4) --------------
// 512 thr = 8 waves (2M x 4N), BK=64, acc[8][4]. LDS 128 KiB = 2 buffers.
// Per K-tile t (buf b=t&1), 2 phases:
//  phase A: ds_read A-mh0 (rows wm*128+0..63) + ALL B (held in regs) ->
//           32 MFMA (m0-3) -> s_barrier (consumption: rows {0-63,128-191}
//           of A and all of B are done block-wide) -> stage tile t+2's
//           A{0-63,128-191} + B(all) into buf b (in-place, row-disjoint
//           from anything still to be read).
//  phase B: ds_read A-mh1 (rows wm*128+64..127) -> 32 MFMA (m4-7) ->
//           s_barrier -> stage tile t+2's A{64-127,192-255} ->
//           vmcnt(8): waits ONLY for tile t+1's 8 loads (issued one full
//           tile ago); the newest 8 (tile t+2) stay in flight. NEVER
//           drains to 0 in steady state. -> s_barrier (availability).
// Chunk-XOR swizzle (chunk ^= row&7) both-sides; XCD-swizzled 1-D grid.
template <int EPI>
__global__ __launch_bounds__(512)
void gemm256p(const ushort* __restrict__ A, const ushort* __restrict__ Bt,
              void* __restrict__ Cout, const float* __restrict__ bias,
              const float* __restrict__ resid, int M, int N, int K, int nbn) {
  extern __shared__ ushort smem[];
  ushort* lA = smem;            // [2][256*64]
  ushort* lB = smem + 32768;    // [2][256*64]

  int tid = threadIdx.x;
  int lane = tid & 63, w = tid >> 6;
  int wm = w >> 2, wn = w & 3;          // 2 x 4 wave grid
  int lrow = lane & 15, lg = lane >> 4;

  int nwg = gridDim.x;
  int cpx = nwg >> 3;
  int wg = ((int)blockIdx.x & 7) * cpx + ((int)blockIdx.x >> 3);
  int bm = wg / nbn, bn = wg % nbn;

  const ushort* Ab = A + (size_t)bm * 256 * K;
  const ushort* Bb = Bt + (size_t)bn * 256 * K;
  int srow = tid >> 3, sch = tid & 7;   // 64 rows per instr, 8 chunks

  auto stageA = [&](int buf, int k0, int rb) {
    int r = rb + srow;
    int gch = sch ^ (r & 7);
    gload_lds16(Ab + (size_t)r * K + k0 + gch * 8,
                &lA[buf * 16384 + rb * 64 + tid * 8]);
  };
  auto stageB = [&](int buf, int k0, int rb) {
    int r = rb + srow;
    int gch = sch ^ (r & 7);
    gload_lds16(Bb + (size_t)r * K + k0 + gch * 8,
                &lB[buf * 16384 + rb * 64 + tid * 8]);
  };

  f32x4 acc[8][4] = {};
  int nt = K >> 6;

  // prologue: stage tiles 0 and 1, wait for tile 0 only
  {
    stageA(0, 0, 0); stageA(0, 0, 64); stageA(0, 0, 128); stageA(0, 0, 192);
    stageB(0, 0, 0); stageB(0, 0, 64); stageB(0, 0, 128); stageB(0, 0, 192);
    stageA(1, 64, 0); stageA(1, 64, 64); stageA(1, 64, 128); stageA(1, 64, 192);
    stageB(1, 64, 0); stageB(1, 64, 64); stageB(1, 64, 128); stageB(1, 64, 192);
  }
  asm volatile("s_waitcnt vmcnt(8)" ::: "memory");
  __builtin_amdgcn_s_barrier();

  for (int t = 0; t < nt; ++t) {
    int b = t & 1;
    const ushort* la = &lA[b * 16384];
    const ushort* lb = &lB[b * 16384];
    bool pf = (t + 2 < nt);
    int k2 = (t + 2) << 6;

    bf16x8 af[4][2], bfr[4][2];

    // ================= phase A: A-mh0 + B(all) -> MFMA m0..3 ==============
#pragma unroll
    for (int m = 0; m < 4; m++) {
      int row = wm * 128 + m * 16 + lrow;
      const ushort* p = &la[row * 64];
      af[m][0] = *(const bf16x8*)(p + (((lg    ) ^ (row & 7)) << 3));
      af[m][1] = *(const bf16x8*)(p + (((lg + 4) ^ (row & 7)) << 3));
    }
#pragma unroll
    for (int n = 0; n < 4; n++) {
      int row = wn * 64 + n * 16 + lrow;
      const ushort* p = &lb[row * 64];
      bfr[n][0] = *(const bf16x8*)(p + (((lg    ) ^ (row & 7)) << 3));
      bfr[n][1] = *(const bf16x8*)(p + (((lg + 4) ^ (row & 7)) << 3));
    }
    __builtin_amdgcn_s_setprio(1);
#pragma unroll
    for (int m = 0; m < 4; m++)
#pragma unroll
      for (int n = 0; n < 4; n++) {
        acc[m][n] = mfma16(af[m][0], bfr[n][0], acc[m][n]);
        acc[m][n] = mfma16(af[m][1], bfr[n][1], acc[m][n]);
      }
    __builtin_amdgcn_s_setprio(0);
    __builtin_amdgcn_s_barrier();        // consumption fence: A{0-63,128-191}, B all
    asm volatile("" ::: "memory");
    if (pf) {
      stageA(b, k2, 0); stageA(b, k2, 128);
      stageB(b, k2, 0); stageB(b, k2, 64); stageB(b, k2, 128); stageB(b, k2, 192);
    }

    // ================= phase B: A-mh1 -> MFMA m4..7 =======================
#pragma unroll
    for (int m = 0; m < 4; m++) {
      int row = wm * 128 + 64 + m * 16 + lrow;
      const ushort* p = &la[row * 64];
      af[m][0] = *(const bf16x8*)(p + (((lg    ) ^ (row & 7)) << 3));
      af[m][1] = *(const bf16x8*)(p + (((lg + 4) ^ (row & 7)) << 3));
    }
    __builtin_amdgcn_s_setprio(1);
#pragma unroll
    for (int m = 0; m < 4; m++)
#pragma unroll
      for (int n = 0; n < 4; n++) {
        acc[m + 4][n] = mfma16(af[m][0], bfr[n][0], acc[m + 4][n]);
        acc[m + 4][n] = mfma16(af[m][1], bfr[n][1], acc[m + 4][n]);
      }
    __builtin_amdgcn_s_setprio(0);
    __builtin_amdgcn_s_barrier();        // consumption fence: A{64-127,192-255}
    asm volatile("" ::: "memory");
    if (pf) { stageA(b, k2, 64); stageA(b, k2, 192); }

    // availability fence for tile t+1 (counted — never drains in steady state)
    if (t + 1 < nt) {
      if (pf) asm volatile("s_waitcnt vmcnt(8)" ::: "memory");
      else    asm volatile("s_waitcnt vmcnt(0)" ::: "memory");
      __builtin_amdgcn_s_barrier();
    }
  }

#pragma unroll
  for (int m = 0; m < 8; m++) {
    int rbase = bm * 256 + wm * 128 + m * 16 + lg * 4;
#pragma unroll
    for (int n = 0; n < 4; n++) {
      int c = bn * 256 + wn * 64 + n * 16 + lrow;
#pragma unroll
      for (int r = 0; r < 4; r++) {
        float v = acc[m][n][r];
        size_t idx = (size_t)(rbase + r) * N + c;
        if constexpr (EPI == 0) {
          ((ushort*)Cout)[idx] = f2bf(v);
        } else if constexpr (EPI == 1) {
          ((float*)Cout)[idx] = v + resid[idx];
        } else if constexpr (EPI == 2) {
          ((ushort*)Cout)[idx] = f2bf(gelu_f(v + bias[c]));
        } else {
          ((float*)Cout)[idx] = v + bias[c] + resid[idx];
        }
      }
    }
  }
}

// ---------------- GEMM 128xBN 2-phase (r7 structure — wo / ffn2) -----------
template <int EPI, int BN>
__global__ __launch_bounds__(256)
void gemm_kernel(const ushort* __restrict__ A, const ushort* __restrict__ Bt,
                 void* __restrict__ Cout, const float* __restrict__ bias,
                 const float* __restrict__ resid, int M, int N, int K,
                 int nbn) {
  constexpr int NF = BN / 32;           // n-frags per wave (4 or 2)
  __shared__ ushort lA[2][128 * 64];
  __shared__ ushort lB[2][BN * 64];
  int tid = threadIdx.x;
  int lane = tid & 63, w = tid >> 6;
  int wm = w >> 1, wn = w & 1;

  int nwg = gridDim.x;
  int cpx = nwg >> 3;
  int wg = ((int)blockIdx.x & 7) * cpx + ((int)blockIdx.x >> 3);
  int bm = wg / nbn, bn = wg % nbn;

  f32x4 acc[4][NF] = {};

  const ushort* Ab = A + (size_t)bm * 128 * K;
  const ushort* Bb = Bt + (size_t)bn * BN * K;
  int lrow = lane & 15, lg = lane >> 4;
  int srow = tid >> 3, sch = tid & 7;

  auto stage = [&](int buf, int k0) {
#pragma unroll
    for (int c = 0; c < 4; c++) {
      int r = c * 32 + srow;
      int gch = sch ^ (r & 7);
      gload_lds16(Ab + (size_t)r * K + k0 + gch * 8,
                  &lA[buf][c * 2048 + tid * 8]);
    }
#pragma unroll
    for (int c = 0; c < NF; c++) {
      int r = c * 32 + srow;
      int gch = sch ^ (r & 7);
      gload_lds16(Bb + (size_t)r * K + k0 + gch * 8,
                  &lB[buf][c * 2048 + tid * 8]);
    }
  };

  int nt = K >> 6;
  stage(0, 0);
  __syncthreads();   // prologue: full drain once

  for (int t = 0; t < nt; ++t) {
    int cur = t & 1;

    bf16x8 af0[4], af1[4], bf0[NF], bf1[NF];
#pragma unroll
    for (int m = 0; m < 4; m++) {
      int row = wm * 64 + m * 16 + lrow;
      const ushort* p = &lA[cur][row * 64];
      af0[m] = *(const bf16x8*)(p + (((lg    ) ^ (row & 7)) << 3));
      af1[m] = *(const bf16x8*)(p + (((lg + 4) ^ (row & 7)) << 3));
    }
#pragma unroll
    for (int n = 0; n < NF; n++) {
      int row = wn * (BN / 2) + n * 16 + lrow;
      const ushort* p = &lB[cur][row * 64];
      bf0[n] = *(const bf16x8*)(p + (((lg    ) ^ (row & 7)) << 3));
      bf1[n] = *(const bf16x8*)(p + (((lg + 4) ^ (row & 7)) << 3));
    }

    if (t + 1 < nt) stage(cur ^ 1, (t + 1) << 6);

    __builtin_amdgcn_s_setprio(1);
#pragma unroll
    for (int m = 0; m < 4; m++)
#pragma unroll
      for (int n = 0; n < NF; n++)
        acc[m][n] = mfma16(af0[m], bf0[n], acc[m][n]);
#pragma unroll
    for (int m = 0; m < 4; m++)
#pragma unroll
      for (int n = 0; n < NF; n++)
        acc[m][n] = mfma16(af1[m], bf1[n], acc[m][n]);
    __builtin_amdgcn_s_setprio(0);

    __builtin_amdgcn_sched_barrier(0);
    asm volatile("s_waitcnt vmcnt(0)" ::: "memory");
    __builtin_amdgcn_s_barrier();
  }

#pragma unroll
  for (int m = 0; m < 4; m++) {
    int rbase = bm * 128 + wm * 64 + m * 16 + (lane >> 4) * 4;
#pragma unroll
    for (int n = 0; n < NF; n++) {
      int c = bn * BN + wn * (BN / 2) + n * 16 + (lane & 15);
#pragma unroll
      for (int r = 0; r < 4; r++) {
        float v = acc[m][n][r];
        size_t idx = (size_t)(rbase + r) * N + c;
        if constexpr (EPI == 0) {
          ((ushort*)Cout)[idx] = f2bf(v);
        } else if constexpr (EPI == 1) {
          ((float*)Cout)[idx] = v + resid[idx];
        } else if constexpr (EPI == 2) {
          ((ushort*)Cout)[idx] = f2bf(gelu_f(v + bias[c]));
        } else {
          ((float*)Cout)[idx] = v + bias[c] + resid[idx];
        }
      }
    }
  }
}

// ---------------------------------------------------------------------------
extern "C" void kernel_launch(void* const* d_in, const int* in_sizes, int n_in,
                              void* d_out, int out_size, void* d_ws,
                              size_t ws_size, hipStream_t stream) {
  const float* x      = (const float*)d_in[0];
  const int* positions = (const int*)d_in[1];
  const float* ln1_s  = (const float*)d_in[3];
  const float* ln1_b  = (const float*)d_in[4];
  const float* w_qkv  = (const float*)d_in[5];
  const float* w_o    = (const float*)d_in[6];
  const float* ln2_s  = (const float*)d_in[7];
  const float* ln2_b  = (const float*)d_in[8];
  const float* w1     = (const float*)d_in[9];
  const float* b1     = (const float*)d_in[10];
  const float* w2     = (const float*)d_in[11];
  const float* b2     = (const float*)d_in[12];
  float* out = (float*)d_out;

  char* ws = (char*)d_ws;
  size_t off = 0;
  auto nxt = [&](size_t bytes) {
    char* p = ws + off;
    off += (bytes + 255) & ~(size_t)255;
    return p;
  };
  ushort* wqkvT = (ushort*)nxt(3072ULL * 1024 * 2);
  ushort* woT   = (ushort*)nxt(1024ULL * 1024 * 2);
  ushort* w1T   = (ushort*)nxt(4096ULL * 1024 * 2);
  ushort* w2T   = (ushort*)nxt(1024ULL * 4096 * 2);
  ushort* h1    = (ushort*)nxt((size_t)M_ROWS * DMODEL * 2);
  ushort* qkv   = (ushort*)nxt((size_t)M_ROWS * 3072 * 2);
  ushort* Qb    = (ushort*)nxt(2ULL * NHEAD * TSEQ * HDIM * 2);
  ushort* Kb    = (ushort*)nxt(2ULL * NHEAD * TSEQ * HDIM * 2);
  ushort* VTb   = (ushort*)nxt(2ULL * NHEAD * TSEQ * HDIM * 2);
  ushort* attn  = (ushort*)nxt((size_t)M_ROWS * DMODEL * 2);
  float*  x2    = (float*)nxt((size_t)M_ROWS * DMODEL * 4);
  ushort* h2    = (ushort*)nxt((size_t)M_ROWS * DMODEL * 2);
  ushort* mid   = (ushort*)nxt((size_t)M_ROWS * 4096 * 2);
  float2* tab   = (float2*)nxt((size_t)TSEQ * 32 * 8);

  // allow 128 KiB dynamic LDS for the 256x256 GEMMs (capture-safe host call)
  (void)hipFuncSetAttribute((const void*)gemm256p<0>,
                            hipFuncAttributeMaxDynamicSharedMemorySize, 131072);
  (void)hipFuncSetAttribute((const void*)gemm256p<2>,
                            hipFuncAttributeMaxDynamicSharedMemorySize, 131072);

  transpose_bf16<<<dim3(3072 / 32, 1024 / 32), 256, 0, stream>>>(w_qkv, wqkvT, 1024, 3072);
  transpose_bf16<<<dim3(1024 / 32, 1024 / 32), 256, 0, stream>>>(w_o, woT, 1024, 1024);
  transpose_bf16<<<dim3(4096 / 32, 1024 / 32), 256, 0, stream>>>(w1, w1T, 1024, 4096);
  transpose_bf16<<<dim3(1024 / 32, 4096 / 32), 256, 0, stream>>>(w2, w2T, 4096, 1024);
  rope_table<<<(TSEQ * 32) / 256, 256, 0, stream>>>(positions, tab);
  ln_kernel<<<M_ROWS, 256, 0, stream>>>(x, ln1_s, ln1_b, h1);
  // qkv: M=4096 N=3072 K=1024, 256x256 tiles -> 16*12=192 wgs
  gemm256p<0><<<192, 512, 131072, stream>>>(h1, wqkvT, qkv, nullptr, nullptr, 4096, 3072, 1024, 12);
  rope_apply<<<dim3(TSEQ / 64, 2 * NHEAD), 256, 0, stream>>>(qkv, tab, Qb, Kb, VTb);
  attn_kernel<<<dim3(32, 32), 256, 0, stream>>>(Qb, Kb, VTb, attn);
  // wo: M=4096 N=1024 K=1024, 128x64 tiles -> 512 wgs
  gemm_kernel<1, 64><<<512, 256, 0, stream>>>(attn, woT, x2, nullptr, x, 4096, 1024, 1024, 16);
  ln_kernel<<<M_ROWS, 256, 0, stream>>>(x2, ln2_s, ln2_b, h2);
  // ffn1: M=4096 N=4096 K=1024, 256x256 tiles -> 16*16=256 wgs
  gemm256p<2><<<256, 512, 131072, stream>>>(h2, w1T, mid, b1, nullptr, 4096, 4096, 1024, 16);
  // ffn2: M=4096 N=1024 K=4096, 128x64 tiles -> 512 wgs
  gemm_kernel<3, 64><<<512, 256, 0, stream>>>(mid, w2T, out, b2, x2, 4096, 1024, 4096, 16);
}